// Round 5
// baseline (325.651 us; speedup 1.0000x reference)
//
#include <hip/hip_runtime.h>
#include <math.h>

#define NB 2
#define NN 2048
#define DD 512

typedef __attribute__((ext_vector_type(8))) short short8;
typedef __attribute__((ext_vector_type(4))) float f32x4;

__device__ __forceinline__ unsigned short f2bf(float x) {
  union { float f; unsigned u; } a;
  a.f = x;
  unsigned r = a.u + 0x7FFF + ((a.u >> 16) & 1);  // RNE
  return (unsigned short)(r >> 16);
}
__device__ __forceinline__ float bf2f(unsigned short u) {
  union { unsigned u; float f; } a;
  a.u = ((unsigned)u) << 16;
  return a.f;
}
// pack two fp32 -> one dword of 2x bf16 (lo = first arg)
__device__ __forceinline__ unsigned cvtpk(float lo, float hi) {
  unsigned r;
  asm("v_cvt_pk_bf16_f32 %0, %1, %2" : "=v"(r) : "v"(lo), "v"(hi));
  return r;
}

__device__ __forceinline__ float waveReduceSum(float v) {
#pragma unroll
  for (int o = 32; o; o >>= 1) v += __shfl_down(v, o, 64);
  return v;
}
__device__ __forceinline__ float waveReduceMax(float v) {
#pragma unroll
  for (int o = 32; o; o >>= 1) v = fmaxf(v, __shfl_down(v, o, 64));
  return v;
}
__device__ __forceinline__ float blockReduceSum(float v, float* red4) {
  int tid = threadIdx.x;
  __syncthreads();
  v = waveReduceSum(v);
  if ((tid & 63) == 0) red4[tid >> 6] = v;
  __syncthreads();
  return red4[0] + red4[1] + red4[2] + red4[3];
}
__device__ __forceinline__ float blockReduceMax(float v, float* red4) {
  int tid = threadIdx.x;
  __syncthreads();
  v = waveReduceMax(v);
  if ((tid & 63) == 0) red4[tid >> 6] = v;
  __syncthreads();
  return fmaxf(fmaxf(red4[0], red4[1]), fmaxf(red4[2], red4[3]));
}

// ---------------- LayerNorm -> bf16: one block (256 thr) per row of 512 --------
__global__ __launch_bounds__(256) void ln_kernel(const float* __restrict__ x,
                                                 const float* __restrict__ g,
                                                 const float* __restrict__ bb,
                                                 unsigned short* __restrict__ y) {
  int row = blockIdx.x;
  int t = threadIdx.x;
  const float* xr = x + (size_t)row * DD;
  __shared__ float red4[4];
  float2 v = *(const float2*)&xr[2 * t];
  float s = blockReduceSum(v.x + v.y, red4);
  float mu = s * (1.0f / 512.0f);
  float d0 = v.x - mu, d1 = v.y - mu;
  float ss = blockReduceSum(d0 * d0 + d1 * d1, red4);
  float rstd = rsqrtf(ss * (1.0f / 512.0f) + 1e-6f);
  float2 gg = *(const float2*)&g[2 * t];
  float2 bv = *(const float2*)&bb[2 * t];
  ushort2 o;
  o.x = f2bf(d0 * rstd * gg.x + bv.x);
  o.y = f2bf(d1 * rstd * gg.y + bv.y);
  *(ushort2*)&y[(size_t)row * DD + 2 * t] = o;
}

// ---------------- W [512k][512c] fp32 -> WT [c][k] bf16 ------------------------
__global__ __launch_bounds__(256) void wt_kernel(const float* __restrict__ W,
                                                 unsigned short* __restrict__ WT) {
  __shared__ float tile[64][65];
  int kt = blockIdx.x * 64, ct = blockIdx.y * 64;
  int t = threadIdx.x;
#pragma unroll
  for (int u = 0; u < 16; u++) {
    int lin = t + u * 256;
    int kl = lin >> 6, cl = lin & 63;
    tile[kl][cl] = W[(size_t)(kt + kl) * DD + ct + cl];
  }
  __syncthreads();
#pragma unroll
  for (int u = 0; u < 16; u++) {
    int lin = t + u * 256;
    int cl = lin >> 6, kl = lin & 63;
    WT[(size_t)(ct + cl) * DD + kt + kl] = f2bf(tile[kl][cl]);
  }
}

// ---------------- v = W @ a  (per head): vs/vd are [H][512] fp32 ---------------
__global__ __launch_bounds__(256) void v_kernel(const float* __restrict__ W,
                                                const float* __restrict__ asrc,
                                                const float* __restrict__ adst,
                                                float* __restrict__ vs,
                                                float* __restrict__ vd, int HN, int Dh) {
  int t = threadIdx.x;
  int dl = t >> 2, kq = t & 3;
  int d = blockIdx.x * 64 + dl;
  int kn = Dh >> 2;
  for (int h = 0; h < HN; h++) {
    const float* wr = W + (size_t)d * DD + h * Dh + kq * kn;
    const float* as = asrc + h * Dh + kq * kn;
    const float* ad = adst + h * Dh + kq * kn;
    float s = 0.f, dd2 = 0.f;
    for (int k = 0; k < kn; k++) {
      float wv = wr[k];
      s += wv * as[k];
      dd2 += wv * ad[k];
    }
    s += __shfl_xor(s, 1);
    s += __shfl_xor(s, 2);
    dd2 += __shfl_xor(dd2, 1);
    dd2 += __shfl_xor(dd2, 2);
    if (kq == 0) {
      vs[(size_t)h * DD + d] = s;
      vd[(size_t)h * DD + d] = dd2;
    }
  }
}

// ---------------- bmax[b*NN+i] = max_j bias[b][i][j] ---------------------------
__global__ __launch_bounds__(256) void bmax_kernel(const float* __restrict__ bias,
                                                   float* __restrict__ bmax) {
  int row = blockIdx.x;  // b*NN + i
  int t = threadIdx.x;
  __shared__ float red4[4];
  const float* br = bias + (size_t)row * NN;
  float4 a = *(const float4*)&br[t * 4];
  float4 c = *(const float4*)&br[t * 4 + 1024];
  float lm = fmaxf(fmaxf(fmaxf(a.x, a.y), fmaxf(a.z, a.w)),
                   fmaxf(fmaxf(c.x, c.y), fmaxf(c.z, c.w)));
  float m = blockReduceMax(lm, red4);
  if (t == 0) bmax[row] = m;
}

// ---------------- M[bh][i] = lrelu(s_i + tmax_bh) + bmax[b][i] -----------------
__global__ __launch_bounds__(256) void mprep_kernel(const float* __restrict__ sArr,
                                                    const float* __restrict__ tArr,
                                                    const float* __restrict__ bmax,
                                                    float* __restrict__ mArr, int HN) {
  int bh = blockIdx.x;
  int b = bh / HN;
  int t = threadIdx.x;
  __shared__ float red4[4];
  size_t bhN = (size_t)bh * NN;
  const float* trow = tArr + bhN;
  float4 a = *(const float4*)&trow[t * 4];
  float4 c = *(const float4*)&trow[t * 4 + 1024];
  float lm = fmaxf(fmaxf(fmaxf(a.x, a.y), fmaxf(a.z, a.w)),
                   fmaxf(fmaxf(c.x, c.y), fmaxf(c.z, c.w)));
  float tmax = blockReduceMax(lm, red4);
  for (int i = t; i < NN; i += 256) {
    float e = sArr[bhN + i] + tmax;
    e = fmaxf(e, 0.2f * e);
    mArr[bhN + i] = e + bmax[(size_t)b * NN + i];
  }
}

// ---------------- bf16 MFMA GEMM, K-split: hbT[b][c][j] = bf16( lnB @ W ) ------
__global__ __launch_bounds__(256) void gemm_kernel(const unsigned short* __restrict__ A,
                                                   const unsigned short* __restrict__ BT,
                                                   unsigned short* __restrict__ hbT) {
  __shared__ float accL[4][16][65];
  int t = threadIdx.x, w = t >> 6, l = t & 63;
  int li = l & 15, lg = l >> 4;
  int R0 = blockIdx.x * 16;  // global row (b*NN + j)
  int c0 = blockIdx.y * 64;
  const unsigned short* ar = A + (size_t)(R0 + li) * DD + w * 128 + lg * 8;
  const unsigned short* br = BT + (size_t)(c0 + li) * DD + w * 128 + lg * 8;
  f32x4 acc[4] = {};
#pragma unroll
  for (int k0 = 0; k0 < 128; k0 += 32) {
    short8 af = *(const short8*)(ar + k0);
#pragma unroll
    for (int f = 0; f < 4; f++) {
      short8 bf = *(const short8*)(br + (size_t)f * 16 * DD + k0);
      acc[f] = __builtin_amdgcn_mfma_f32_16x16x32_bf16(af, bf, acc[f], 0, 0, 0);
    }
  }
#pragma unroll
  for (int f = 0; f < 4; f++)
#pragma unroll
    for (int r = 0; r < 4; r++) accL[w][lg * 4 + r][f * 16 + li] = acc[f][r];
  __syncthreads();
  int b = R0 >> 11, j0 = R0 & (NN - 1);
#pragma unroll
  for (int u = 0; u < 4; u++) {
    int idx = t + u * 256;  // 1024 outputs: c = idx>>4, r = idx&15
    int c = idx >> 4, r = idx & 15;
    float v = accL[0][r][c] + accL[1][r][c] + accL[2][r][c] + accL[3][r][c];
    hbT[((size_t)b * DD + c0 + c) * NN + j0 + r] = f2bf(v);
  }
}

// ---------------- s,t: wave per row; s = lnrow . vs[h], t = lnrow . vd[h] ------
__global__ __launch_bounds__(256) void st_kernel(const unsigned short* __restrict__ lnB,
                                                 const float* __restrict__ vs,
                                                 const float* __restrict__ vd,
                                                 float* __restrict__ sOut,
                                                 float* __restrict__ tOut, int HN) {
  int t = threadIdx.x, w = t >> 6, l = t & 63;
  int row = blockIdx.x * 4 + w;
  int b = row >> 11, n = row & (NN - 1);
  const unsigned short* lr = lnB + (size_t)row * DD + l * 8;
  union { short8 v; unsigned short u[8]; } xv;
  xv.v = *(const short8*)lr;
  float xf[8];
#pragma unroll
  for (int k = 0; k < 8; k++) xf[k] = bf2f(xv.u[k]);
  for (int h = 0; h < HN; h++) {
    const float* vsr = vs + (size_t)h * DD + l * 8;
    const float* vdr = vd + (size_t)h * DD + l * 8;
    float4 a0 = *(const float4*)vsr, a1 = *(const float4*)(vsr + 4);
    float4 c0 = *(const float4*)vdr, c1 = *(const float4*)(vdr + 4);
    float ps = xf[0] * a0.x + xf[1] * a0.y + xf[2] * a0.z + xf[3] * a0.w +
               xf[4] * a1.x + xf[5] * a1.y + xf[6] * a1.z + xf[7] * a1.w;
    float pd = xf[0] * c0.x + xf[1] * c0.y + xf[2] * c0.z + xf[3] * c0.w +
               xf[4] * c1.x + xf[5] * c1.y + xf[6] * c1.z + xf[7] * c1.w;
#pragma unroll
    for (int o = 32; o; o >>= 1) {
      ps += __shfl_xor(ps, o);
      pd += __shfl_xor(pd, o);
    }
    if (l == 0) {
      sOut[((size_t)b * HN + h) * NN + n] = ps;
      tOut[((size_t)b * HN + h) * NN + n] = pd;
    }
  }
}

// ---------------- fused PV, precomputed shift M => straight-line inner loop ----
// Block: out tile 16 rows x 64 cols; wave w covers j in [w*NN/4, (w+1)*NN/4).
// p = exp(lrelu(s_i+t_j)+bias_ij - M_i) <= 1 guaranteed; partials merge by SUM.
// Lane l computes P[row=l&15][j=(l>>4)*8..+8] straight into the MFMA A-fragment.
template <int HN>
__global__ __launch_bounds__(256) void pv_kernel(const unsigned short* __restrict__ hbT,
                                                 const float* __restrict__ bias,
                                                 const float* __restrict__ sArr,
                                                 const float* __restrict__ tArr,
                                                 const float* __restrict__ mArr,
                                                 const float* __restrict__ res,
                                                 float* __restrict__ out) {
  constexpr int DH = DD / HN;
  __shared__ float accL[4][16][65];
  __shared__ float sL[4][16];
  int t = threadIdx.x, w = t >> 6, l = t & 63;
  int li = l & 15, lg = l >> 4;
  int it = blockIdx.x;
  int ck = blockIdx.y;
  int bh = blockIdx.z;
  int h = bh % HN, b = bh / HN;
  int i0 = it * 16;
  int c0 = h * DH + ck * 64;
  int i = i0 + li;
  size_t bhN = (size_t)bh * NN;
  float si = sArr[bhN + i];
  float Mi = mArr[bhN + i];
  const float* trow = tArr + bhN;
  const float* brow = bias + ((size_t)b * NN + i) * NN;
  const unsigned short* vb = hbT + ((size_t)b * DD + c0 + li) * NN + lg * 8;

  const int JW = NN / 4;
  const int jbeg = w * JW, jend = jbeg + JW;

  f32x4 acc[4] = {};
  float msum = 0.f;

  // 1-deep register prefetch of t, bias, V
  float4 nt0, nt1, nb0, nb1;
  short8 nv0, nv1, nv2, nv3;
  {
    int jb = jbeg + lg * 8;
    nt0 = *(const float4*)&trow[jb];
    nt1 = *(const float4*)&trow[jb + 4];
    nb0 = *(const float4*)&brow[jb];
    nb1 = *(const float4*)&brow[jb + 4];
    nv0 = *(const short8*)(vb + jbeg);
    nv1 = *(const short8*)(vb + (size_t)16 * NN + jbeg);
    nv2 = *(const short8*)(vb + (size_t)32 * NN + jbeg);
    nv3 = *(const short8*)(vb + (size_t)48 * NN + jbeg);
  }
  for (int j0 = jbeg; j0 < jend; j0 += 32) {
    float4 t0 = nt0, t1 = nt1, bb0 = nb0, bb1 = nb1;
    short8 vf0 = nv0, vf1 = nv1, vf2 = nv2, vf3 = nv3;
    if (j0 + 32 < jend) {
      int jb = j0 + 32 + lg * 8;
      nt0 = *(const float4*)&trow[jb];
      nt1 = *(const float4*)&trow[jb + 4];
      nb0 = *(const float4*)&brow[jb];
      nb1 = *(const float4*)&brow[jb + 4];
      nv0 = *(const short8*)(vb + j0 + 32);
      nv1 = *(const short8*)(vb + (size_t)16 * NN + j0 + 32);
      nv2 = *(const short8*)(vb + (size_t)32 * NN + j0 + 32);
      nv3 = *(const short8*)(vb + (size_t)48 * NN + j0 + 32);
    }
    float e[8];
    e[0] = si + t0.x; e[1] = si + t0.y; e[2] = si + t0.z; e[3] = si + t0.w;
    e[4] = si + t1.x; e[5] = si + t1.y; e[6] = si + t1.z; e[7] = si + t1.w;
#pragma unroll
    for (int k = 0; k < 8; k++) e[k] = fmaxf(e[k], 0.2f * e[k]);  // leaky relu
    e[0] += bb0.x; e[1] += bb0.y; e[2] += bb0.z; e[3] += bb0.w;
    e[4] += bb1.x; e[5] += bb1.y; e[6] += bb1.z; e[7] += bb1.w;
    float p[8];
#pragma unroll
    for (int k = 0; k < 8; k++) p[k] = __expf(e[k] - Mi);
    msum += ((p[0] + p[1]) + (p[2] + p[3])) + ((p[4] + p[5]) + (p[6] + p[7]));
    union { short8 v; unsigned u[4]; } a;
    a.u[0] = cvtpk(p[0], p[1]);
    a.u[1] = cvtpk(p[2], p[3]);
    a.u[2] = cvtpk(p[4], p[5]);
    a.u[3] = cvtpk(p[6], p[7]);
    acc[0] = __builtin_amdgcn_mfma_f32_16x16x32_bf16(a.v, vf0, acc[0], 0, 0, 0);
    acc[1] = __builtin_amdgcn_mfma_f32_16x16x32_bf16(a.v, vf1, acc[1], 0, 0, 0);
    acc[2] = __builtin_amdgcn_mfma_f32_16x16x32_bf16(a.v, vf2, acc[2], 0, 0, 0);
    acc[3] = __builtin_amdgcn_mfma_f32_16x16x32_bf16(a.v, vf3, acc[3], 0, 0, 0);
  }
  // per-wave row sums (same shift M for all waves => merge is a plain sum)
  float srow = msum + __shfl_xor(msum, 16);
  srow += __shfl_xor(srow, 32);
  if (l < 16) sL[w][li] = srow;
#pragma unroll
  for (int f = 0; f < 4; f++)
#pragma unroll
    for (int r = 0; r < 4; r++) accL[w][lg * 4 + r][f * 16 + li] = acc[f][r];
  __syncthreads();
  // block merge: 256 threads cover 16 rows x 16 col-quads
  int r = t >> 4, cq = t & 15;
  float S = sL[0][r] + sL[1][r] + sL[2][r] + sL[3][r];
  float4 O;
  O.x = accL[0][r][cq * 4 + 0] + accL[1][r][cq * 4 + 0] + accL[2][r][cq * 4 + 0] +
        accL[3][r][cq * 4 + 0];
  O.y = accL[0][r][cq * 4 + 1] + accL[1][r][cq * 4 + 1] + accL[2][r][cq * 4 + 1] +
        accL[3][r][cq * 4 + 1];
  O.z = accL[0][r][cq * 4 + 2] + accL[1][r][cq * 4 + 2] + accL[2][r][cq * 4 + 2] +
        accL[3][r][cq * 4 + 2];
  O.w = accL[0][r][cq * 4 + 3] + accL[1][r][cq * 4 + 3] + accL[2][r][cq * 4 + 3] +
        accL[3][r][cq * 4 + 3];
  float inv = 1.0f / S;
  size_t ix = ((size_t)b * NN + i0 + r) * DD + c0 + cq * 4;
  float4 rv = *(const float4*)&res[ix];
  float4 ov;
  ov.x = O.x * inv + rv.x;
  ov.y = O.y * inv + rv.y;
  ov.z = O.z * inv + rv.z;
  ov.w = O.w * inv + rv.w;
  *(float4*)&out[ix] = ov;
}

extern "C" void kernel_launch(void* const* d_in, const int* in_sizes, int n_in,
                              void* d_out, int out_size, void* d_ws, size_t ws_size,
                              hipStream_t stream) {
  const float* x = (const float*)d_in[0];
  const float* bias = (const float*)d_in[1];
  const float* W1 = (const float*)d_in[2];
  const float* asrc1 = (const float*)d_in[3];
  const float* adst1 = (const float*)d_in[4];
  const float* g1 = (const float*)d_in[5];
  const float* b1 = (const float*)d_in[6];
  const float* W2 = (const float*)d_in[7];
  const float* asrc2 = (const float*)d_in[8];
  const float* adst2 = (const float*)d_in[9];
  const float* g2 = (const float*)d_in[10];
  const float* b2 = (const float*)d_in[11];
  float* out = (float*)d_out;
  float* ws = (float*)d_ws;

  const size_t RC = (size_t)NB * NN * DD;  // 2097152
  float* attnBuf = ws;                                        // 8 MB fp32
  unsigned short* lnB = (unsigned short*)(ws + RC);           // 4 MB bf16
  unsigned short* hbT = (unsigned short*)(ws + RC + RC / 2);  // 4 MB bf16
  unsigned short* WT1 = (unsigned short*)(ws + 2 * RC);       // 0.5 MB
  unsigned short* WT2 = WT1 + (size_t)DD * DD;                // 0.5 MB
  float* vs1 = (float*)(WT2 + (size_t)DD * DD);               // [8][512]
  float* vd1 = vs1 + 8 * DD;
  float* vs2 = vd1 + 8 * DD;  // [1][512]
  float* vd2 = vs2 + DD;
  float* sBuf = vd2 + DD;  // [16][2048]
  float* tBuf = sBuf + 16 * NN;
  float* mBuf = tBuf + 16 * NN;    // [16][2048]
  float* bmaxBuf = mBuf + 16 * NN; // [2][2048]

  const int rows = NB * NN;  // 4096

  // ---- input prep (no deps on x) ----
  hipLaunchKernelGGL(wt_kernel, dim3(8, 8), dim3(256), 0, stream, W1, WT1);
  hipLaunchKernelGGL(wt_kernel, dim3(8, 8), dim3(256), 0, stream, W2, WT2);
  hipLaunchKernelGGL(v_kernel, dim3(8), dim3(256), 0, stream, W1, asrc1, adst1, vs1, vd1, 8, 64);
  hipLaunchKernelGGL(v_kernel, dim3(8), dim3(256), 0, stream, W2, asrc2, adst2, vs2, vd2, 1, 512);
  hipLaunchKernelGGL(bmax_kernel, dim3(rows), dim3(256), 0, stream, bias, bmaxBuf);

  // ---- layer 1 (H=8, Dh=64) ----
  hipLaunchKernelGGL(ln_kernel, dim3(rows), dim3(256), 0, stream, x, g1, b1, lnB);
  hipLaunchKernelGGL(gemm_kernel, dim3(256, 8), dim3(256), 0, stream, lnB, WT1, hbT);
  hipLaunchKernelGGL(st_kernel, dim3(rows / 4), dim3(256), 0, stream, lnB, vs1, vd1, sBuf, tBuf, 8);
  hipLaunchKernelGGL(mprep_kernel, dim3(NB * 8), dim3(256), 0, stream, sBuf, tBuf, bmaxBuf,
                     mBuf, 8);
  hipLaunchKernelGGL(pv_kernel<8>, dim3(128, 1, 16), dim3(256), 0, stream, hbT, bias, sBuf, tBuf,
                     mBuf, x, attnBuf);

  // ---- layer 2 (H=1, Dh=512) ----
  hipLaunchKernelGGL(ln_kernel, dim3(rows), dim3(256), 0, stream, attnBuf, g2, b2, lnB);
  hipLaunchKernelGGL(gemm_kernel, dim3(256, 8), dim3(256), 0, stream, lnB, WT2, hbT);
  hipLaunchKernelGGL(st_kernel, dim3(rows / 4), dim3(256), 0, stream, lnB, vs2, vd2, sBuf, tBuf, 1);
  hipLaunchKernelGGL(mprep_kernel, dim3(NB * 1), dim3(256), 0, stream, sBuf, tBuf, bmaxBuf,
                     mBuf, 1);
  hipLaunchKernelGGL(pv_kernel<1>, dim3(128, 8, 2), dim3(256), 0, stream, hbT, bias, sBuf, tBuf,
                     mBuf, attnBuf, out);
}

// Round 7
// 208.794 us; speedup vs baseline: 1.5597x; 1.5597x over previous
//
#include <hip/hip_runtime.h>
#include <math.h>

#define NB 2
#define NN 2048
#define DD 512

typedef __attribute__((ext_vector_type(8))) short short8;
typedef __attribute__((ext_vector_type(4))) float f32x4;

__device__ __forceinline__ unsigned short f2bf(float x) {
  union { float f; unsigned u; } a;
  a.f = x;
  unsigned r = a.u + 0x7FFF + ((a.u >> 16) & 1);  // RNE
  return (unsigned short)(r >> 16);
}
__device__ __forceinline__ float bf2f(unsigned short u) {
  union { unsigned u; float f; } a;
  a.u = ((unsigned)u) << 16;
  return a.f;
}
// pack two fp32 -> one dword of 2x bf16 (lo = first arg)
__device__ __forceinline__ unsigned cvtpk(float lo, float hi) {
  unsigned r;
  asm("v_cvt_pk_bf16_f32 %0, %1, %2" : "=v"(r) : "v"(lo), "v"(hi));
  return r;
}

__device__ __forceinline__ float waveReduceSum(float v) {
#pragma unroll
  for (int o = 32; o; o >>= 1) v += __shfl_down(v, o, 64);
  return v;
}
__device__ __forceinline__ float waveReduceMax(float v) {
#pragma unroll
  for (int o = 32; o; o >>= 1) v = fmaxf(v, __shfl_down(v, o, 64));
  return v;
}
__device__ __forceinline__ float blockReduceSum(float v, float* red4) {
  int tid = threadIdx.x;
  __syncthreads();
  v = waveReduceSum(v);
  if ((tid & 63) == 0) red4[tid >> 6] = v;
  __syncthreads();
  return red4[0] + red4[1] + red4[2] + red4[3];
}
__device__ __forceinline__ float blockReduceMax(float v, float* red4) {
  int tid = threadIdx.x;
  __syncthreads();
  v = waveReduceMax(v);
  if ((tid & 63) == 0) red4[tid >> 6] = v;
  __syncthreads();
  return fmaxf(fmaxf(red4[0], red4[1]), fmaxf(red4[2], red4[3]));
}

// ---------------- LayerNorm -> bf16: one block (256 thr) per row of 512 --------
__global__ __launch_bounds__(256) void ln_kernel(const float* __restrict__ x,
                                                 const float* __restrict__ g,
                                                 const float* __restrict__ bb,
                                                 unsigned short* __restrict__ y) {
  int row = blockIdx.x;
  int t = threadIdx.x;
  const float* xr = x + (size_t)row * DD;
  __shared__ float red4[4];
  float2 v = *(const float2*)&xr[2 * t];
  float s = blockReduceSum(v.x + v.y, red4);
  float mu = s * (1.0f / 512.0f);
  float d0 = v.x - mu, d1 = v.y - mu;
  float ss = blockReduceSum(d0 * d0 + d1 * d1, red4);
  float rstd = rsqrtf(ss * (1.0f / 512.0f) + 1e-6f);
  float2 gg = *(const float2*)&g[2 * t];
  float2 bv = *(const float2*)&bb[2 * t];
  ushort2 o;
  o.x = f2bf(d0 * rstd * gg.x + bv.x);
  o.y = f2bf(d1 * rstd * gg.y + bv.y);
  *(ushort2*)&y[(size_t)row * DD + 2 * t] = o;
}

// ---------------- W [512k][512c] fp32 -> WT [c][k] bf16 ------------------------
__global__ __launch_bounds__(256) void wt_kernel(const float* __restrict__ W,
                                                 unsigned short* __restrict__ WT) {
  __shared__ float tile[64][65];
  int kt = blockIdx.x * 64, ct = blockIdx.y * 64;
  int t = threadIdx.x;
#pragma unroll
  for (int u = 0; u < 16; u++) {
    int lin = t + u * 256;
    int kl = lin >> 6, cl = lin & 63;
    tile[kl][cl] = W[(size_t)(kt + kl) * DD + ct + cl];
  }
  __syncthreads();
#pragma unroll
  for (int u = 0; u < 16; u++) {
    int lin = t + u * 256;
    int cl = lin >> 6, kl = lin & 63;
    WT[(size_t)(ct + cl) * DD + kt + kl] = f2bf(tile[kl][cl]);
  }
}

// ---------------- v = W @ a  (per head): vs/vd are [H][512] fp32 ---------------
__global__ __launch_bounds__(256) void v_kernel(const float* __restrict__ W,
                                                const float* __restrict__ asrc,
                                                const float* __restrict__ adst,
                                                float* __restrict__ vs,
                                                float* __restrict__ vd, int HN, int Dh) {
  int t = threadIdx.x;
  int dl = t >> 2, kq = t & 3;
  int d = blockIdx.x * 64 + dl;
  int kn = Dh >> 2;
  for (int h = 0; h < HN; h++) {
    const float* wr = W + (size_t)d * DD + h * Dh + kq * kn;
    const float* as = asrc + h * Dh + kq * kn;
    const float* ad = adst + h * Dh + kq * kn;
    float s = 0.f, dd2 = 0.f;
    for (int k = 0; k < kn; k++) {
      float wv = wr[k];
      s += wv * as[k];
      dd2 += wv * ad[k];
    }
    s += __shfl_xor(s, 1);
    s += __shfl_xor(s, 2);
    dd2 += __shfl_xor(dd2, 1);
    dd2 += __shfl_xor(dd2, 2);
    if (kq == 0) {
      vs[(size_t)h * DD + d] = s;
      vd[(size_t)h * DD + d] = dd2;
    }
  }
}

// ---------------- bmax[b*NN+i] = max_j bias[b][i][j] ---------------------------
__global__ __launch_bounds__(256) void bmax_kernel(const float* __restrict__ bias,
                                                   float* __restrict__ bmax) {
  int row = blockIdx.x;  // b*NN + i
  int t = threadIdx.x;
  __shared__ float red4[4];
  const float* br = bias + (size_t)row * NN;
  float4 a = *(const float4*)&br[t * 4];
  float4 c = *(const float4*)&br[t * 4 + 1024];
  float lm = fmaxf(fmaxf(fmaxf(a.x, a.y), fmaxf(a.z, a.w)),
                   fmaxf(fmaxf(c.x, c.y), fmaxf(c.z, c.w)));
  float m = blockReduceMax(lm, red4);
  if (t == 0) bmax[row] = m;
}

// ---------------- M[bh][i] = lrelu(s_i + tmax_bh) + bmax[b][i] -----------------
__global__ __launch_bounds__(256) void mprep_kernel(const float* __restrict__ sArr,
                                                    const float* __restrict__ tArr,
                                                    const float* __restrict__ bmax,
                                                    float* __restrict__ mArr, int HN) {
  int bh = blockIdx.x;
  int b = bh / HN;
  int t = threadIdx.x;
  __shared__ float red4[4];
  size_t bhN = (size_t)bh * NN;
  const float* trow = tArr + bhN;
  float4 a = *(const float4*)&trow[t * 4];
  float4 c = *(const float4*)&trow[t * 4 + 1024];
  float lm = fmaxf(fmaxf(fmaxf(a.x, a.y), fmaxf(a.z, a.w)),
                   fmaxf(fmaxf(c.x, c.y), fmaxf(c.z, c.w)));
  float tmax = blockReduceMax(lm, red4);
  for (int i = t; i < NN; i += 256) {
    float e = sArr[bhN + i] + tmax;
    e = fmaxf(e, 0.2f * e);
    mArr[bhN + i] = e + bmax[(size_t)b * NN + i];
  }
}

// ------- bf16 MFMA GEMM, K-split; epilogue writes V in TILED layout ------------
// hbT layout: [b][cT=c/16][jT=j/16][cl=16][jl=16] bf16 (512B tiles) so that an
// MFMA B-fragment load (64 lanes x 16B) is 1KB contiguous = 8 full lines.
__global__ __launch_bounds__(256) void gemm_kernel(const unsigned short* __restrict__ A,
                                                   const unsigned short* __restrict__ BT,
                                                   unsigned short* __restrict__ hbT) {
  __shared__ float accL[4][16][65];
  int t = threadIdx.x, w = t >> 6, l = t & 63;
  int li = l & 15, lg = l >> 4;
  int R0 = blockIdx.x * 16;  // global row (b*NN + j)
  int c0 = blockIdx.y * 64;
  const unsigned short* ar = A + (size_t)(R0 + li) * DD + w * 128 + lg * 8;
  const unsigned short* br = BT + (size_t)(c0 + li) * DD + w * 128 + lg * 8;
  f32x4 acc[4] = {};
#pragma unroll
  for (int k0 = 0; k0 < 128; k0 += 32) {
    short8 af = *(const short8*)(ar + k0);
#pragma unroll
    for (int f = 0; f < 4; f++) {
      short8 bf = *(const short8*)(br + (size_t)f * 16 * DD + k0);
      acc[f] = __builtin_amdgcn_mfma_f32_16x16x32_bf16(af, bf, acc[f], 0, 0, 0);
    }
  }
#pragma unroll
  for (int f = 0; f < 4; f++)
#pragma unroll
    for (int r = 0; r < 4; r++) accL[w][lg * 4 + r][f * 16 + li] = acc[f][r];
  __syncthreads();
  int b = R0 >> 11, jT = (R0 & (NN - 1)) >> 4;
  int cT0 = c0 >> 4;
#pragma unroll
  for (int u = 0; u < 2; u++) {
    int idx = t + u * 256;  // 512 dwords = 16j x 64c
    int f = idx >> 7;
    int rem = idx & 127;
    int cl = rem >> 3, jlp = rem & 7;
    int cc = f * 16 + cl;
    float v0 = accL[0][2 * jlp][cc] + accL[1][2 * jlp][cc] + accL[2][2 * jlp][cc] +
               accL[3][2 * jlp][cc];
    float v1 = accL[0][2 * jlp + 1][cc] + accL[1][2 * jlp + 1][cc] +
               accL[2][2 * jlp + 1][cc] + accL[3][2 * jlp + 1][cc];
    size_t off = (((size_t)(b * (DD / 16) + cT0 + f) * (NN / 16)) + jT) * 256 +
                 cl * 16 + jlp * 2;
    *(unsigned*)(hbT + off) = cvtpk(v0, v1);
  }
}

// ---------------- s,t: wave per row; s = lnrow . vs[h], t = lnrow . vd[h] ------
__global__ __launch_bounds__(256) void st_kernel(const unsigned short* __restrict__ lnB,
                                                 const float* __restrict__ vs,
                                                 const float* __restrict__ vd,
                                                 float* __restrict__ sOut,
                                                 float* __restrict__ tOut, int HN) {
  int t = threadIdx.x, w = t >> 6, l = t & 63;
  int row = blockIdx.x * 4 + w;
  int b = row >> 11, n = row & (NN - 1);
  const unsigned short* lr = lnB + (size_t)row * DD + l * 8;
  union { short8 v; unsigned short u[8]; } xv;
  xv.v = *(const short8*)lr;
  float xf[8];
#pragma unroll
  for (int k = 0; k < 8; k++) xf[k] = bf2f(xv.u[k]);
  for (int h = 0; h < HN; h++) {
    const float* vsr = vs + (size_t)h * DD + l * 8;
    const float* vdr = vd + (size_t)h * DD + l * 8;
    float4 a0 = *(const float4*)vsr, a1 = *(const float4*)(vsr + 4);
    float4 c0 = *(const float4*)vdr, c1 = *(const float4*)(vdr + 4);
    float ps = xf[0] * a0.x + xf[1] * a0.y + xf[2] * a0.z + xf[3] * a0.w +
               xf[4] * a1.x + xf[5] * a1.y + xf[6] * a1.z + xf[7] * a1.w;
    float pd = xf[0] * c0.x + xf[1] * c0.y + xf[2] * c0.z + xf[3] * c0.w +
               xf[4] * c1.x + xf[5] * c1.y + xf[6] * c1.z + xf[7] * c1.w;
#pragma unroll
    for (int o = 32; o; o >>= 1) {
      ps += __shfl_xor(ps, o);
      pd += __shfl_xor(pd, o);
    }
    if (l == 0) {
      sOut[((size_t)b * HN + h) * NN + n] = ps;
      tOut[((size_t)b * HN + h) * NN + n] = pd;
    }
  }
}

// ---------------- fused PV: LDS-staged P (coalesced bias), tiled V -------------
// Block: 32 rows x 64 cols; wave w covers j in [w*512, w*512+512), j-tiles of 32.
// Staging lanes: row = (l>>3)+u*8, j = jt+(l&7)*4 -> bias float4 insts cover 8
// full 128B lines. P tile (32x32 bf16) lives in a PER-WAVE LDS buffer with a
// 16B-quad swizzle (quad ^= row&3); no __syncthreads in the j-loop.
template <int HN>
__global__ __launch_bounds__(256) void pv_kernel(
    const unsigned short* __restrict__ hbT, const float* __restrict__ bias,
    const float* __restrict__ sArr, const float* __restrict__ tArr,
    const float* __restrict__ mArr, const float* __restrict__ res,
    float* __restrict__ out) {
  constexpr int DH = DD / HN;
  __shared__ unsigned short Pl[4][1024];  // per-wave 32x32 bf16 (swizzled)
  __shared__ float accL[4][32][33];       // merge, 32-col halves
  __shared__ float sL[4][32];
  int t = threadIdx.x, w = t >> 6, l = t & 63;
  int li = l & 15, lg = l >> 4;
  int i0 = blockIdx.x * 32;
  int ck = blockIdx.y, bh = blockIdx.z;
  int h = bh % HN, b = bh / HN;
  int c0 = h * DH + ck * 64;
  size_t bhN = (size_t)bh * NN;

  // staging constants
  int rs = l >> 3;                        // 0..7
  int js = (l & 7) * 4;                   // 0..28
  int wq = (((l & 7) >> 1) ^ (rs & 3)) * 8 + (l & 1) * 4;  // swizzled shorts off
  float sv[4], Mv[4];
#pragma unroll
  for (int u = 0; u < 4; u++) {
    sv[u] = sArr[bhN + i0 + u * 8 + rs];
    Mv[u] = mArr[bhN + i0 + u * 8 + rs];
  }
  const float* trow = tArr + bhN;
  const float* bb = bias + ((size_t)b * NN + i0) * NN;

  // V (tiled) lane pointer: frag f at +f*32768, j-tile jt at +jt*16 shorts
  const unsigned short* vb =
      hbT + (((size_t)(b * (DD / 16) + (c0 >> 4)) * (NN / 16) + (lg >> 1)) * 256) +
      li * 16 + (lg & 1) * 8;
  // A-frag swizzled read offsets (shorts)
  int ra0 = li * 32 + ((lg ^ (li & 3)) * 8);
  int ra1 = (16 + li) * 32 + ((lg ^ (li & 3)) * 8);

  const int jbeg = w * (NN / 4), jend = jbeg + NN / 4;
  f32x4 acc[2][4] = {};
  float psum[4] = {0.f, 0.f, 0.f, 0.f};

  short8 nv0 = *(const short8*)(vb + (size_t)jbeg * 16);
  short8 nv1 = *(const short8*)(vb + (size_t)jbeg * 16 + 32768);
  short8 nv2 = *(const short8*)(vb + (size_t)jbeg * 16 + 65536);
  short8 nv3 = *(const short8*)(vb + (size_t)jbeg * 16 + 98304);

  for (int jt = jbeg; jt < jend; jt += 32) {
    float4 tv = *(const float4*)&trow[jt + js];
#pragma unroll
    for (int u = 0; u < 4; u++) {
      int row = u * 8 + rs;
      float4 bv = *(const float4*)&bb[(size_t)row * NN + jt + js];
      float e0 = sv[u] + tv.x;
      float e1 = sv[u] + tv.y;
      float e2 = sv[u] + tv.z;
      float e3 = sv[u] + tv.w;
      e0 = fmaxf(e0, 0.2f * e0) + bv.x;
      e1 = fmaxf(e1, 0.2f * e1) + bv.y;
      e2 = fmaxf(e2, 0.2f * e2) + bv.z;
      e3 = fmaxf(e3, 0.2f * e3) + bv.w;
      float p0 = __expf(e0 - Mv[u]);
      float p1 = __expf(e1 - Mv[u]);
      float p2 = __expf(e2 - Mv[u]);
      float p3 = __expf(e3 - Mv[u]);
      psum[u] += (p0 + p1) + (p2 + p3);
      uint2 d;
      d.x = cvtpk(p0, p1);
      d.y = cvtpk(p2, p3);
      *(uint2*)&Pl[w][row * 32 + wq] = d;
    }
    // MFMA phase (same wave reads only its own Pl[w]; compiler orders LDS ops)
    short8 v0 = nv0, v1 = nv1, v2 = nv2, v3 = nv3;
    if (jt + 32 < jend) {
      nv0 = *(const short8*)(vb + (size_t)(jt + 32) * 16);
      nv1 = *(const short8*)(vb + (size_t)(jt + 32) * 16 + 32768);
      nv2 = *(const short8*)(vb + (size_t)(jt + 32) * 16 + 65536);
      nv3 = *(const short8*)(vb + (size_t)(jt + 32) * 16 + 98304);
    }
    short8 a0 = *(const short8*)&Pl[w][ra0];
    short8 a1 = *(const short8*)&Pl[w][ra1];
    acc[0][0] = __builtin_amdgcn_mfma_f32_16x16x32_bf16(a0, v0, acc[0][0], 0, 0, 0);
    acc[0][1] = __builtin_amdgcn_mfma_f32_16x16x32_bf16(a0, v1, acc[0][1], 0, 0, 0);
    acc[0][2] = __builtin_amdgcn_mfma_f32_16x16x32_bf16(a0, v2, acc[0][2], 0, 0, 0);
    acc[0][3] = __builtin_amdgcn_mfma_f32_16x16x32_bf16(a0, v3, acc[0][3], 0, 0, 0);
    acc[1][0] = __builtin_amdgcn_mfma_f32_16x16x32_bf16(a1, v0, acc[1][0], 0, 0, 0);
    acc[1][1] = __builtin_amdgcn_mfma_f32_16x16x32_bf16(a1, v1, acc[1][1], 0, 0, 0);
    acc[1][2] = __builtin_amdgcn_mfma_f32_16x16x32_bf16(a1, v2, acc[1][2], 0, 0, 0);
    acc[1][3] = __builtin_amdgcn_mfma_f32_16x16x32_bf16(a1, v3, acc[1][3], 0, 0, 0);
  }
  // per-row sums: reduce over the 8 staging lanes of each row
#pragma unroll
  for (int u = 0; u < 4; u++) {
    float r = psum[u];
    r += __shfl_xor(r, 1);
    r += __shfl_xor(r, 2);
    r += __shfl_xor(r, 4);
    if ((l & 7) == 0) sL[w][u * 8 + rs] = r;
  }
  // pass 0: cols 0..31 (frags 0,1)
#pragma unroll
  for (int rb = 0; rb < 2; rb++)
#pragma unroll
    for (int f = 0; f < 2; f++)
#pragma unroll
      for (int r = 0; r < 4; r++)
        accL[w][rb * 16 + lg * 4 + r][f * 16 + li] = acc[rb][f][r];
  __syncthreads();
  {
    int rr = t >> 3, cc = (t & 7) * 4;
    float S = sL[0][rr] + sL[1][rr] + sL[2][rr] + sL[3][rr];
    float inv = 1.0f / S;
    float4 O;
    O.x = accL[0][rr][cc + 0] + accL[1][rr][cc + 0] + accL[2][rr][cc + 0] + accL[3][rr][cc + 0];
    O.y = accL[0][rr][cc + 1] + accL[1][rr][cc + 1] + accL[2][rr][cc + 1] + accL[3][rr][cc + 1];
    O.z = accL[0][rr][cc + 2] + accL[1][rr][cc + 2] + accL[2][rr][cc + 2] + accL[3][rr][cc + 2];
    O.w = accL[0][rr][cc + 3] + accL[1][rr][cc + 3] + accL[2][rr][cc + 3] + accL[3][rr][cc + 3];
    size_t ix = ((size_t)b * NN + i0 + rr) * DD + c0 + cc;
    float4 rv = *(const float4*)&res[ix];
    float4 ov = {O.x * inv + rv.x, O.y * inv + rv.y, O.z * inv + rv.z, O.w * inv + rv.w};
    *(float4*)&out[ix] = ov;
  }
  __syncthreads();
  // pass 1: cols 32..63 (frags 2,3)
#pragma unroll
  for (int rb = 0; rb < 2; rb++)
#pragma unroll
    for (int f = 2; f < 4; f++)
#pragma unroll
      for (int r = 0; r < 4; r++)
        accL[w][rb * 16 + lg * 4 + r][(f - 2) * 16 + li] = acc[rb][f][r];
  __syncthreads();
  {
    int rr = t >> 3, cc = (t & 7) * 4;
    float S = sL[0][rr] + sL[1][rr] + sL[2][rr] + sL[3][rr];
    float inv = 1.0f / S;
    float4 O;
    O.x = accL[0][rr][cc + 0] + accL[1][rr][cc + 0] + accL[2][rr][cc + 0] + accL[3][rr][cc + 0];
    O.y = accL[0][rr][cc + 1] + accL[1][rr][cc + 1] + accL[2][rr][cc + 1] + accL[3][rr][cc + 1];
    O.z = accL[0][rr][cc + 2] + accL[1][rr][cc + 2] + accL[2][rr][cc + 2] + accL[3][rr][cc + 2];
    O.w = accL[0][rr][cc + 3] + accL[1][rr][cc + 3] + accL[2][rr][cc + 3] + accL[3][rr][cc + 3];
    size_t ix = ((size_t)b * NN + i0 + rr) * DD + c0 + 32 + cc;
    float4 rv = *(const float4*)&res[ix];
    float4 ov = {O.x * inv + rv.x, O.y * inv + rv.y, O.z * inv + rv.z, O.w * inv + rv.w};
    *(float4*)&out[ix] = ov;
  }
}

extern "C" void kernel_launch(void* const* d_in, const int* in_sizes, int n_in,
                              void* d_out, int out_size, void* d_ws, size_t ws_size,
                              hipStream_t stream) {
  const float* x = (const float*)d_in[0];
  const float* bias = (const float*)d_in[1];
  const float* W1 = (const float*)d_in[2];
  const float* asrc1 = (const float*)d_in[3];
  const float* adst1 = (const float*)d_in[4];
  const float* g1 = (const float*)d_in[5];
  const float* b1 = (const float*)d_in[6];
  const float* W2 = (const float*)d_in[7];
  const float* asrc2 = (const float*)d_in[8];
  const float* adst2 = (const float*)d_in[9];
  const float* g2 = (const float*)d_in[10];
  const float* b2 = (const float*)d_in[11];
  float* out = (float*)d_out;
  float* ws = (float*)d_ws;

  const size_t RC = (size_t)NB * NN * DD;  // 2097152 floats
  float* attnBuf = ws;                                        // 8 MB fp32
  unsigned short* lnB = (unsigned short*)(ws + RC);           // 4 MB bf16
  unsigned short* hbT = (unsigned short*)(ws + RC + RC / 2);  // 4 MB bf16 tiled V
  unsigned short* WT1 = (unsigned short*)(ws + 2 * RC);       // 0.5 MB
  unsigned short* WT2 = WT1 + (size_t)DD * DD;                // 0.5 MB
  float* vs1 = (float*)(WT2 + (size_t)DD * DD);               // [8][512]
  float* vd1 = vs1 + 8 * DD;
  float* vs2 = vd1 + 8 * DD;  // [1][512]
  float* vd2 = vs2 + DD;
  float* sBuf = vd2 + DD;  // [16][2048]
  float* tBuf = sBuf + 16 * NN;
  float* mBuf = tBuf + 16 * NN;     // [16][2048]
  float* bmaxB = mBuf + 16 * NN;    // [2][2048]

  const int rows = NB * NN;  // 4096

  // ---- input prep (no deps on x) ----
  hipLaunchKernelGGL(wt_kernel, dim3(8, 8), dim3(256), 0, stream, W1, WT1);
  hipLaunchKernelGGL(wt_kernel, dim3(8, 8), dim3(256), 0, stream, W2, WT2);
  hipLaunchKernelGGL(v_kernel, dim3(8), dim3(256), 0, stream, W1, asrc1, adst1, vs1, vd1, 8, 64);
  hipLaunchKernelGGL(v_kernel, dim3(8), dim3(256), 0, stream, W2, asrc2, adst2, vs2, vd2, 1, 512);
  hipLaunchKernelGGL(bmax_kernel, dim3(rows), dim3(256), 0, stream, bias, bmaxB);

  // ---- layer 1 (H=8, Dh=64) ----
  hipLaunchKernelGGL(ln_kernel, dim3(rows), dim3(256), 0, stream, x, g1, b1, lnB);
  hipLaunchKernelGGL(gemm_kernel, dim3(256, 8), dim3(256), 0, stream, lnB, WT1, hbT);
  hipLaunchKernelGGL(st_kernel, dim3(rows / 4), dim3(256), 0, stream, lnB, vs1, vd1, sBuf, tBuf, 8);
  hipLaunchKernelGGL(mprep_kernel, dim3(NB * 8), dim3(256), 0, stream, sBuf, tBuf, bmaxB,
                     mBuf, 8);
  hipLaunchKernelGGL(pv_kernel<8>, dim3(64, 1, 16), dim3(256), 0, stream, hbT, bias, sBuf,
                     tBuf, mBuf, x, attnBuf);

  // ---- layer 2 (H=1, Dh=512) ----
  hipLaunchKernelGGL(ln_kernel, dim3(rows), dim3(256), 0, stream, attnBuf, g2, b2, lnB);
  hipLaunchKernelGGL(gemm_kernel, dim3(256, 8), dim3(256), 0, stream, lnB, WT2, hbT);
  hipLaunchKernelGGL(st_kernel, dim3(rows / 4), dim3(256), 0, stream, lnB, vs2, vd2, sBuf, tBuf, 1);
  hipLaunchKernelGGL(mprep_kernel, dim3(NB * 1), dim3(256), 0, stream, sBuf, tBuf, bmaxB,
                     mBuf, 1);
  hipLaunchKernelGGL(pv_kernel<1>, dim3(64, 8, 2), dim3(256), 0, stream, hbT, bias, sBuf,
                     tBuf, mBuf, attnBuf, out);
}

// Round 8
// 160.687 us; speedup vs baseline: 2.0266x; 1.2994x over previous
//
#include <hip/hip_runtime.h>
#include <math.h>

#define NB 2
#define NN 2048
#define DD 512

typedef __attribute__((ext_vector_type(8))) short short8;
typedef __attribute__((ext_vector_type(4))) float f32x4;

__device__ __forceinline__ unsigned short f2bf(float x) {
  union { float f; unsigned u; } a;
  a.f = x;
  unsigned r = a.u + 0x7FFF + ((a.u >> 16) & 1);  // RNE
  return (unsigned short)(r >> 16);
}
__device__ __forceinline__ float bf2f(unsigned short u) {
  union { unsigned u; float f; } a;
  a.u = ((unsigned)u) << 16;
  return a.f;
}
// pack two fp32 -> one dword of 2x bf16 (lo = first arg)
__device__ __forceinline__ unsigned cvtpk(float lo, float hi) {
  unsigned r;
  asm("v_cvt_pk_bf16_f32 %0, %1, %2" : "=v"(r) : "v"(lo), "v"(hi));
  return r;
}

__device__ __forceinline__ float waveReduceSum(float v) {
#pragma unroll
  for (int o = 32; o; o >>= 1) v += __shfl_down(v, o, 64);
  return v;
}
__device__ __forceinline__ float waveReduceMax(float v) {
#pragma unroll
  for (int o = 32; o; o >>= 1) v = fmaxf(v, __shfl_down(v, o, 64));
  return v;
}
__device__ __forceinline__ float blockReduceSum(float v, float* red4) {
  int tid = threadIdx.x;
  __syncthreads();
  v = waveReduceSum(v);
  if ((tid & 63) == 0) red4[tid >> 6] = v;
  __syncthreads();
  return red4[0] + red4[1] + red4[2] + red4[3];
}
__device__ __forceinline__ float blockReduceMax(float v, float* red4) {
  int tid = threadIdx.x;
  __syncthreads();
  v = waveReduceMax(v);
  if ((tid & 63) == 0) red4[tid >> 6] = v;
  __syncthreads();
  return fmaxf(fmaxf(red4[0], red4[1]), fmaxf(red4[2], red4[3]));
}

// ---------------- LayerNorm -> bf16: one block (256 thr) per row of 512 --------
__global__ __launch_bounds__(256) void ln_kernel(const float* __restrict__ x,
                                                 const float* __restrict__ g,
                                                 const float* __restrict__ bb,
                                                 unsigned short* __restrict__ y) {
  int row = blockIdx.x;
  int t = threadIdx.x;
  const float* xr = x + (size_t)row * DD;
  __shared__ float red4[4];
  float2 v = *(const float2*)&xr[2 * t];
  float s = blockReduceSum(v.x + v.y, red4);
  float mu = s * (1.0f / 512.0f);
  float d0 = v.x - mu, d1 = v.y - mu;
  float ss = blockReduceSum(d0 * d0 + d1 * d1, red4);
  float rstd = rsqrtf(ss * (1.0f / 512.0f) + 1e-6f);
  float2 gg = *(const float2*)&g[2 * t];
  float2 bv = *(const float2*)&bb[2 * t];
  ushort2 o;
  o.x = f2bf(d0 * rstd * gg.x + bv.x);
  o.y = f2bf(d1 * rstd * gg.y + bv.y);
  *(ushort2*)&y[(size_t)row * DD + 2 * t] = o;
}

// -------- both W's: W [512k][512c] fp32 -> WT [c][k] bf16 (z picks layer) ------
__global__ __launch_bounds__(256) void wt2_kernel(const float* __restrict__ W1,
                                                  const float* __restrict__ W2,
                                                  unsigned short* __restrict__ WT1,
                                                  unsigned short* __restrict__ WT2) {
  const float* W = blockIdx.z ? W2 : W1;
  unsigned short* WT = blockIdx.z ? WT2 : WT1;
  __shared__ float tile[64][65];
  int kt = blockIdx.x * 64, ct = blockIdx.y * 64;
  int t = threadIdx.x;
#pragma unroll
  for (int u = 0; u < 16; u++) {
    int lin = t + u * 256;
    int kl = lin >> 6, cl = lin & 63;
    tile[kl][cl] = W[(size_t)(kt + kl) * DD + ct + cl];
  }
  __syncthreads();
#pragma unroll
  for (int u = 0; u < 16; u++) {
    int lin = t + u * 256;
    int cl = lin >> 6, kl = lin & 63;
    WT[(size_t)(ct + cl) * DD + kt + kl] = f2bf(tile[kl][cl]);
  }
}

// ------- v = W @ a for all head-slots of both layers in ONE launch -------------
// grid (8 d-chunks, 9 slots): slot<8 -> layer1 head slot; slot==8 -> layer2.
__global__ __launch_bounds__(256) void v2_kernel(
    const float* __restrict__ W1, const float* __restrict__ as1,
    const float* __restrict__ ad1, float* __restrict__ vs1, float* __restrict__ vd1,
    const float* __restrict__ W2, const float* __restrict__ as2,
    const float* __restrict__ ad2, float* __restrict__ vs2, float* __restrict__ vd2) {
  int slot = blockIdx.y;
  const float *W, *as, *ad;
  float *vs, *vd;
  int Dh, hoff;
  if (slot < 8) {
    W = W1; as = as1 + slot * 64; ad = ad1 + slot * 64;
    vs = vs1 + (size_t)slot * DD; vd = vd1 + (size_t)slot * DD;
    Dh = 64; hoff = slot * 64;
  } else {
    W = W2; as = as2; ad = ad2; vs = vs2; vd = vd2;
    Dh = 512; hoff = 0;
  }
  int t = threadIdx.x;
  int dl = t >> 2, kq = t & 3;
  int d = blockIdx.x * 64 + dl;
  int kn = Dh >> 2;
  const float* wr = W + (size_t)d * DD + hoff + kq * kn;
  const float* asp = as + kq * kn;
  const float* adp = ad + kq * kn;
  float s = 0.f, dd2 = 0.f;
  for (int k = 0; k < kn; k++) {
    float wv = wr[k];
    s += wv * asp[k];
    dd2 += wv * adp[k];
  }
  s += __shfl_xor(s, 1);
  s += __shfl_xor(s, 2);
  dd2 += __shfl_xor(dd2, 1);
  dd2 += __shfl_xor(dd2, 2);
  if (kq == 0) {
    vs[d] = s;
    vd[d] = dd2;
  }
}

// ---------------- bmax[b*NN+i] = max_j bias[b][i][j] ---------------------------
__global__ __launch_bounds__(256) void bmax_kernel(const float* __restrict__ bias,
                                                   float* __restrict__ bmax) {
  int row = blockIdx.x;  // b*NN + i
  int t = threadIdx.x;
  __shared__ float red4[4];
  const float* br = bias + (size_t)row * NN;
  float4 a = *(const float4*)&br[t * 4];
  float4 c = *(const float4*)&br[t * 4 + 1024];
  float lm = fmaxf(fmaxf(fmaxf(a.x, a.y), fmaxf(a.z, a.w)),
                   fmaxf(fmaxf(c.x, c.y), fmaxf(c.z, c.w)));
  float m = blockReduceMax(lm, red4);
  if (t == 0) bmax[row] = m;
}

// ------- bf16 MFMA GEMM, K-split; epilogue writes V in TILED layout ------------
// hbT layout: [b][cT=c/16][jT=j/16][cl=16][jl=16] bf16 (512B tiles) so that an
// MFMA B-fragment load (64 lanes x 16B) is 1KB contiguous = 8 full lines.
__global__ __launch_bounds__(256) void gemm_kernel(const unsigned short* __restrict__ A,
                                                   const unsigned short* __restrict__ BT,
                                                   unsigned short* __restrict__ hbT) {
  __shared__ float accL[4][16][65];
  int t = threadIdx.x, w = t >> 6, l = t & 63;
  int li = l & 15, lg = l >> 4;
  int R0 = blockIdx.x * 16;  // global row (b*NN + j)
  int c0 = blockIdx.y * 64;
  const unsigned short* ar = A + (size_t)(R0 + li) * DD + w * 128 + lg * 8;
  const unsigned short* br = BT + (size_t)(c0 + li) * DD + w * 128 + lg * 8;
  f32x4 acc[4] = {};
#pragma unroll
  for (int k0 = 0; k0 < 128; k0 += 32) {
    short8 af = *(const short8*)(ar + k0);
#pragma unroll
    for (int f = 0; f < 4; f++) {
      short8 bf = *(const short8*)(br + (size_t)f * 16 * DD + k0);
      acc[f] = __builtin_amdgcn_mfma_f32_16x16x32_bf16(af, bf, acc[f], 0, 0, 0);
    }
  }
#pragma unroll
  for (int f = 0; f < 4; f++)
#pragma unroll
    for (int r = 0; r < 4; r++) accL[w][lg * 4 + r][f * 16 + li] = acc[f][r];
  __syncthreads();
  int b = R0 >> 11, jT = (R0 & (NN - 1)) >> 4;
  int cT0 = c0 >> 4;
#pragma unroll
  for (int u = 0; u < 2; u++) {
    int idx = t + u * 256;  // 512 dwords = 16j x 64c
    int f = idx >> 7;
    int rem = idx & 127;
    int cl = rem >> 3, jlp = rem & 7;
    int cc = f * 16 + cl;
    float v0 = accL[0][2 * jlp][cc] + accL[1][2 * jlp][cc] + accL[2][2 * jlp][cc] +
               accL[3][2 * jlp][cc];
    float v1 = accL[0][2 * jlp + 1][cc] + accL[1][2 * jlp + 1][cc] +
               accL[2][2 * jlp + 1][cc] + accL[3][2 * jlp + 1][cc];
    size_t off = (((size_t)(b * (DD / 16) + cT0 + f) * (NN / 16)) + jT) * 256 +
                 cl * 16 + jlp * 2;
    *(unsigned*)(hbT + off) = cvtpk(v0, v1);
  }
}

// ---------------- s,t: wave per row; s = lnrow . vs[h], t = lnrow . vd[h] ------
__global__ __launch_bounds__(256) void st_kernel(const unsigned short* __restrict__ lnB,
                                                 const float* __restrict__ vs,
                                                 const float* __restrict__ vd,
                                                 float* __restrict__ sOut,
                                                 float* __restrict__ tOut, int HN) {
  int t = threadIdx.x, w = t >> 6, l = t & 63;
  int row = blockIdx.x * 4 + w;
  int b = row >> 11, n = row & (NN - 1);
  const unsigned short* lr = lnB + (size_t)row * DD + l * 8;
  union { short8 v; unsigned short u[8]; } xv;
  xv.v = *(const short8*)lr;
  float xf[8];
#pragma unroll
  for (int k = 0; k < 8; k++) xf[k] = bf2f(xv.u[k]);
  for (int h = 0; h < HN; h++) {
    const float* vsr = vs + (size_t)h * DD + l * 8;
    const float* vdr = vd + (size_t)h * DD + l * 8;
    float4 a0 = *(const float4*)vsr, a1 = *(const float4*)(vsr + 4);
    float4 c0 = *(const float4*)vdr, c1 = *(const float4*)(vdr + 4);
    float ps = xf[0] * a0.x + xf[1] * a0.y + xf[2] * a0.z + xf[3] * a0.w +
               xf[4] * a1.x + xf[5] * a1.y + xf[6] * a1.z + xf[7] * a1.w;
    float pd = xf[0] * c0.x + xf[1] * c0.y + xf[2] * c0.z + xf[3] * c0.w +
               xf[4] * c1.x + xf[5] * c1.y + xf[6] * c1.z + xf[7] * c1.w;
#pragma unroll
    for (int o = 32; o; o >>= 1) {
      ps += __shfl_xor(ps, o);
      pd += __shfl_xor(pd, o);
    }
    if (l == 0) {
      sOut[((size_t)b * HN + h) * NN + n] = ps;
      tOut[((size_t)b * HN + h) * NN + n] = pd;
    }
  }
}

// ---------------- fused PV: in-block tmax/M, prefetched bias/t, tiled V --------
// Block: 32 rows x 64 cols; wave w covers j in [w*512, w*512+512), j-tiles of 32.
// M_i = lrelu(s_i+tmax)+bmax_i guarantees P<=1; merge is a plain sum.
template <int HN>
__global__ __launch_bounds__(256) void pv_kernel(
    const unsigned short* __restrict__ hbT, const float* __restrict__ bias,
    const float* __restrict__ sArr, const float* __restrict__ tArr,
    const float* __restrict__ bmaxA, const float* __restrict__ res,
    float* __restrict__ out) {
  constexpr int DH = DD / HN;
  __shared__ unsigned short Pl[4][1024];  // per-wave 32x32 bf16 (swizzled)
  __shared__ float accL[4][32][33];       // merge, 32-col halves
  __shared__ float sL[4][32];
  __shared__ float red4[4];
  int t = threadIdx.x, w = t >> 6, l = t & 63;
  int li = l & 15, lg = l >> 4;
  int i0 = blockIdx.x * 32;
  int ck = blockIdx.y, bh = blockIdx.z;
  int h = bh % HN, b = bh / HN;
  int c0 = h * DH + ck * 64;
  size_t bhN = (size_t)bh * NN;
  const float* trow = tArr + bhN;

  // cooperative tmax over the full t row (replaces mprep kernel)
  float4 ta = *(const float4*)&trow[t * 8];
  float4 tb = *(const float4*)&trow[t * 8 + 4];
  float lm = fmaxf(fmaxf(fmaxf(ta.x, ta.y), fmaxf(ta.z, ta.w)),
                   fmaxf(fmaxf(tb.x, tb.y), fmaxf(tb.z, tb.w)));
  float tmax = blockReduceMax(lm, red4);

  // staging constants
  int rs = l >> 3;                        // 0..7
  int js = (l & 7) * 4;                   // 0..28
  int wq = (((l & 7) >> 1) ^ (rs & 3)) * 8 + (l & 1) * 4;  // swizzled shorts off
  float sv[4], Mv[4];
#pragma unroll
  for (int u = 0; u < 4; u++) {
    int row = i0 + u * 8 + rs;
    sv[u] = sArr[bhN + row];
    float q = sv[u] + tmax;
    Mv[u] = fmaxf(q, 0.2f * q) + bmaxA[(size_t)b * NN + row];
  }
  const float* bb = bias + ((size_t)b * NN + i0) * NN;

  // V (tiled) lane pointer: frag f at +f*32768, j-tile jt at +jt*16 shorts
  const unsigned short* vb =
      hbT + (((size_t)(b * (DD / 16) + (c0 >> 4)) * (NN / 16) + (lg >> 1)) * 256) +
      li * 16 + (lg & 1) * 8;
  // A-frag swizzled read offsets (shorts)
  int ra0 = li * 32 + ((lg ^ (li & 3)) * 8);
  int ra1 = (16 + li) * 32 + ((lg ^ (li & 3)) * 8);

  const int jbeg = w * (NN / 4), jend = jbeg + NN / 4;
  f32x4 acc[2][4] = {};
  float psum[4] = {0.f, 0.f, 0.f, 0.f};

  // 1-deep prefetch: t, bias (4 rows-of-8 groups), V fragments
  float4 ptv = *(const float4*)&trow[jbeg + js];
  float4 pb0 = *(const float4*)&bb[(size_t)(0 * 8 + rs) * NN + jbeg + js];
  float4 pb1 = *(const float4*)&bb[(size_t)(1 * 8 + rs) * NN + jbeg + js];
  float4 pb2 = *(const float4*)&bb[(size_t)(2 * 8 + rs) * NN + jbeg + js];
  float4 pb3 = *(const float4*)&bb[(size_t)(3 * 8 + rs) * NN + jbeg + js];
  short8 nv0 = *(const short8*)(vb + (size_t)jbeg * 16);
  short8 nv1 = *(const short8*)(vb + (size_t)jbeg * 16 + 32768);
  short8 nv2 = *(const short8*)(vb + (size_t)jbeg * 16 + 65536);
  short8 nv3 = *(const short8*)(vb + (size_t)jbeg * 16 + 98304);

  for (int jt = jbeg; jt < jend; jt += 32) {
    float4 tv = ptv;
    float4 bv0 = pb0, bv1 = pb1, bv2 = pb2, bv3 = pb3;
    short8 v0 = nv0, v1 = nv1, v2 = nv2, v3 = nv3;
    if (jt + 32 < jend) {
      int jb = jt + 32 + js;
      ptv = *(const float4*)&trow[jb];
      pb0 = *(const float4*)&bb[(size_t)(0 * 8 + rs) * NN + jb];
      pb1 = *(const float4*)&bb[(size_t)(1 * 8 + rs) * NN + jb];
      pb2 = *(const float4*)&bb[(size_t)(2 * 8 + rs) * NN + jb];
      pb3 = *(const float4*)&bb[(size_t)(3 * 8 + rs) * NN + jb];
      nv0 = *(const short8*)(vb + (size_t)(jt + 32) * 16);
      nv1 = *(const short8*)(vb + (size_t)(jt + 32) * 16 + 32768);
      nv2 = *(const short8*)(vb + (size_t)(jt + 32) * 16 + 65536);
      nv3 = *(const short8*)(vb + (size_t)(jt + 32) * 16 + 98304);
    }
#pragma unroll
    for (int u = 0; u < 4; u++) {
      float4 bv = u == 0 ? bv0 : (u == 1 ? bv1 : (u == 2 ? bv2 : bv3));
      int row = u * 8 + rs;
      float e0 = sv[u] + tv.x;
      float e1 = sv[u] + tv.y;
      float e2 = sv[u] + tv.z;
      float e3 = sv[u] + tv.w;
      e0 = fmaxf(e0, 0.2f * e0) + bv.x;
      e1 = fmaxf(e1, 0.2f * e1) + bv.y;
      e2 = fmaxf(e2, 0.2f * e2) + bv.z;
      e3 = fmaxf(e3, 0.2f * e3) + bv.w;
      float p0 = __expf(e0 - Mv[u]);
      float p1 = __expf(e1 - Mv[u]);
      float p2 = __expf(e2 - Mv[u]);
      float p3 = __expf(e3 - Mv[u]);
      psum[u] += (p0 + p1) + (p2 + p3);
      uint2 d;
      d.x = cvtpk(p0, p1);
      d.y = cvtpk(p2, p3);
      *(uint2*)&Pl[w][row * 32 + wq] = d;
    }
    // MFMA phase (same wave reads only its own Pl[w]; waitcnt orders LDS ops)
    short8 a0 = *(const short8*)&Pl[w][ra0];
    short8 a1 = *(const short8*)&Pl[w][ra1];
    __builtin_amdgcn_s_setprio(1);
    acc[0][0] = __builtin_amdgcn_mfma_f32_16x16x32_bf16(a0, v0, acc[0][0], 0, 0, 0);
    acc[0][1] = __builtin_amdgcn_mfma_f32_16x16x32_bf16(a0, v1, acc[0][1], 0, 0, 0);
    acc[0][2] = __builtin_amdgcn_mfma_f32_16x16x32_bf16(a0, v2, acc[0][2], 0, 0, 0);
    acc[0][3] = __builtin_amdgcn_mfma_f32_16x16x32_bf16(a0, v3, acc[0][3], 0, 0, 0);
    acc[1][0] = __builtin_amdgcn_mfma_f32_16x16x32_bf16(a1, v0, acc[1][0], 0, 0, 0);
    acc[1][1] = __builtin_amdgcn_mfma_f32_16x16x32_bf16(a1, v1, acc[1][1], 0, 0, 0);
    acc[1][2] = __builtin_amdgcn_mfma_f32_16x16x32_bf16(a1, v2, acc[1][2], 0, 0, 0);
    acc[1][3] = __builtin_amdgcn_mfma_f32_16x16x32_bf16(a1, v3, acc[1][3], 0, 0, 0);
    __builtin_amdgcn_s_setprio(0);
  }
  // per-row sums: reduce over the 8 staging lanes of each row
#pragma unroll
  for (int u = 0; u < 4; u++) {
    float r = psum[u];
    r += __shfl_xor(r, 1);
    r += __shfl_xor(r, 2);
    r += __shfl_xor(r, 4);
    if ((l & 7) == 0) sL[w][u * 8 + rs] = r;
  }
  // pass 0: cols 0..31 (frags 0,1)
#pragma unroll
  for (int rb = 0; rb < 2; rb++)
#pragma unroll
    for (int f = 0; f < 2; f++)
#pragma unroll
      for (int r = 0; r < 4; r++)
        accL[w][rb * 16 + lg * 4 + r][f * 16 + li] = acc[rb][f][r];
  __syncthreads();
  {
    int rr = t >> 3, cc = (t & 7) * 4;
    float S = sL[0][rr] + sL[1][rr] + sL[2][rr] + sL[3][rr];
    float inv = 1.0f / S;
    float4 O;
    O.x = accL[0][rr][cc + 0] + accL[1][rr][cc + 0] + accL[2][rr][cc + 0] + accL[3][rr][cc + 0];
    O.y = accL[0][rr][cc + 1] + accL[1][rr][cc + 1] + accL[2][rr][cc + 1] + accL[3][rr][cc + 1];
    O.z = accL[0][rr][cc + 2] + accL[1][rr][cc + 2] + accL[2][rr][cc + 2] + accL[3][rr][cc + 2];
    O.w = accL[0][rr][cc + 3] + accL[1][rr][cc + 3] + accL[2][rr][cc + 3] + accL[3][rr][cc + 3];
    size_t ix = ((size_t)b * NN + i0 + rr) * DD + c0 + cc;
    float4 rv = *(const float4*)&res[ix];
    float4 ov = {O.x * inv + rv.x, O.y * inv + rv.y, O.z * inv + rv.z, O.w * inv + rv.w};
    *(float4*)&out[ix] = ov;
  }
  __syncthreads();
  // pass 1: cols 32..63 (frags 2,3)
#pragma unroll
  for (int rb = 0; rb < 2; rb++)
#pragma unroll
    for (int f = 2; f < 4; f++)
#pragma unroll
      for (int r = 0; r < 4; r++)
        accL[w][rb * 16 + lg * 4 + r][(f - 2) * 16 + li] = acc[rb][f][r];
  __syncthreads();
  {
    int rr = t >> 3, cc = (t & 7) * 4;
    float S = sL[0][rr] + sL[1][rr] + sL[2][rr] + sL[3][rr];
    float inv = 1.0f / S;
    float4 O;
    O.x = accL[0][rr][cc + 0] + accL[1][rr][cc + 0] + accL[2][rr][cc + 0] + accL[3][rr][cc + 0];
    O.y = accL[0][rr][cc + 1] + accL[1][rr][cc + 1] + accL[2][rr][cc + 1] + accL[3][rr][cc + 1];
    O.z = accL[0][rr][cc + 2] + accL[1][rr][cc + 2] + accL[2][rr][cc + 2] + accL[3][rr][cc + 2];
    O.w = accL[0][rr][cc + 3] + accL[1][rr][cc + 3] + accL[2][rr][cc + 3] + accL[3][rr][cc + 3];
    size_t ix = ((size_t)b * NN + i0 + rr) * DD + c0 + 32 + cc;
    float4 rv = *(const float4*)&res[ix];
    float4 ov = {O.x * inv + rv.x, O.y * inv + rv.y, O.z * inv + rv.z, O.w * inv + rv.w};
    *(float4*)&out[ix] = ov;
  }
}

extern "C" void kernel_launch(void* const* d_in, const int* in_sizes, int n_in,
                              void* d_out, int out_size, void* d_ws, size_t ws_size,
                              hipStream_t stream) {
  const float* x = (const float*)d_in[0];
  const float* bias = (const float*)d_in[1];
  const float* W1 = (const float*)d_in[2];
  const float* asrc1 = (const float*)d_in[3];
  const float* adst1 = (const float*)d_in[4];
  const float* g1 = (const float*)d_in[5];
  const float* b1 = (const float*)d_in[6];
  const float* W2 = (const float*)d_in[7];
  const float* asrc2 = (const float*)d_in[8];
  const float* adst2 = (const float*)d_in[9];
  const float* g2 = (const float*)d_in[10];
  const float* b2 = (const float*)d_in[11];
  float* out = (float*)d_out;
  float* ws = (float*)d_ws;

  const size_t RC = (size_t)NB * NN * DD;  // 2097152 floats
  float* attnBuf = ws;                                        // 8 MB fp32
  unsigned short* lnB = (unsigned short*)(ws + RC);           // 4 MB bf16
  unsigned short* hbT = (unsigned short*)(ws + RC + RC / 2);  // 4 MB bf16 tiled V
  unsigned short* WT1 = (unsigned short*)(ws + 2 * RC);       // 0.5 MB
  unsigned short* WT2 = WT1 + (size_t)DD * DD;                // 0.5 MB
  float* vs1 = (float*)(WT2 + (size_t)DD * DD);               // [8][512]
  float* vd1 = vs1 + 8 * DD;
  float* vs2 = vd1 + 8 * DD;  // [1][512]
  float* vd2 = vs2 + DD;
  float* sBuf = vd2 + DD;  // [16][2048]
  float* tBuf = sBuf + 16 * NN;
  float* bmaxB = tBuf + 16 * NN;  // [2][2048]

  const int rows = NB * NN;  // 4096

  // ---- input prep (no deps on x) ----
  hipLaunchKernelGGL(wt2_kernel, dim3(8, 8, 2), dim3(256), 0, stream, W1, W2, WT1, WT2);
  hipLaunchKernelGGL(v2_kernel, dim3(8, 9), dim3(256), 0, stream, W1, asrc1, adst1, vs1, vd1,
                     W2, asrc2, adst2, vs2, vd2);
  hipLaunchKernelGGL(bmax_kernel, dim3(rows), dim3(256), 0, stream, bias, bmaxB);

  // ---- layer 1 (H=8, Dh=64) ----
  hipLaunchKernelGGL(ln_kernel, dim3(rows), dim3(256), 0, stream, x, g1, b1, lnB);
  hipLaunchKernelGGL(gemm_kernel, dim3(256, 8), dim3(256), 0, stream, lnB, WT1, hbT);
  hipLaunchKernelGGL(st_kernel, dim3(rows / 4), dim3(256), 0, stream, lnB, vs1, vd1, sBuf, tBuf, 8);
  hipLaunchKernelGGL(pv_kernel<8>, dim3(64, 1, 16), dim3(256), 0, stream, hbT, bias, sBuf,
                     tBuf, bmaxB, x, attnBuf);

  // ---- layer 2 (H=1, Dh=512) ----
  hipLaunchKernelGGL(ln_kernel, dim3(rows), dim3(256), 0, stream, attnBuf, g2, b2, lnB);
  hipLaunchKernelGGL(gemm_kernel, dim3(256, 8), dim3(256), 0, stream, lnB, WT2, hbT);
  hipLaunchKernelGGL(st_kernel, dim3(rows / 4), dim3(256), 0, stream, lnB, vs2, vd2, sBuf, tBuf, 1);
  hipLaunchKernelGGL(pv_kernel<1>, dim3(64, 8, 2), dim3(256), 0, stream, hbT, bias, sBuf,
                     tBuf, bmaxB, attnBuf, out);
}